// Round 3
// baseline (578.835 us; speedup 1.0000x reference)
//
#include <hip/hip_runtime.h>

typedef unsigned short u16;
typedef __attribute__((ext_vector_type(8))) __bf16 bf16x8;
typedef __attribute__((ext_vector_type(4))) float f32x4;

// Problem constants
#define BB 4
#define TT 2048
#define EE 2048
#define HH 16
#define KVH 4
#define DD 128
// KVb: (B*T, 1024): cols [0,512) = K heads, [512,1024) = V heads

static __device__ __forceinline__ u16 f2bf(float f) {
  unsigned int u = __float_as_uint(f);
  u += 0x7fffu + ((u >> 16) & 1u);
  return (u16)(u >> 16);
}

// async global->LDS, 16B per lane. LDS dest is wave-uniform base + lane*16;
// all call sites pass per-lane pointers that are linear in lane with stride 16B.
static __device__ __forceinline__ void gl_lds16(const u16* g, u16* l) {
  __builtin_amdgcn_global_load_lds((__attribute__((address_space(1))) void*)g,
                                   (__attribute__((address_space(3))) void*)l,
                                   16, 0, 0);
}

// ---------------- fp32 -> bf16 convert ----------------
__global__ __launch_bounds__(256) void cvt_f32_bf16(const float* __restrict__ in,
                                                    u16* __restrict__ out, int n4) {
  int i = blockIdx.x * 256 + threadIdx.x;
  if (i >= n4) return;
  float4 v = ((const float4*)in)[i];
  union { uint2 u2; u16 s[4]; } o;
  o.s[0] = f2bf(v.x); o.s[1] = f2bf(v.y); o.s[2] = f2bf(v.z); o.s[3] = f2bf(v.w);
  ((uint2*)out)[i] = o.u2;
}

// ---------------- W (R x C) fp32 -> W^T (C x R) bf16 ----------------
__global__ __launch_bounds__(256) void transpose_w(const float* __restrict__ W,
                                                   u16* __restrict__ Wt, int R, int C) {
  __shared__ float tile[32][33];
  int tx = threadIdx.x & 31, ty = threadIdx.x >> 5;
  int r0 = blockIdx.y * 32, c0 = blockIdx.x * 32;
  #pragma unroll
  for (int i = ty; i < 32; i += 8)
    tile[i][tx] = W[(size_t)(r0 + i) * C + (c0 + tx)];
  __syncthreads();
  #pragma unroll
  for (int i = ty; i < 32; i += 8)
    Wt[(size_t)(c0 + i) * R + (r0 + tx)] = f2bf(tile[tx][i]);
}

// ---------------- V (bf16, token-major) -> VTg (d-major) ----------------
__global__ __launch_bounds__(256) void transpose_v(const u16* __restrict__ KVb,
                                                   u16* __restrict__ VTg) {
  __shared__ u16 tile[32][36];
  const int tid = threadIdx.x;
  const int t0 = blockIdx.x * 32, d0 = blockIdx.y * 32;
  const int z = blockIdx.z;                       // b*4 + kvh
  const int vb = z * 128;
  const size_t srcbase = (size_t)(z >> 2) * TT * 1024 + 512 + (z & 3) * 128;
  {
    int i = tid >> 3, c4 = (tid & 7) * 4;
    union { uint2 u; u16 s[4]; } r;
    r.u = *(const uint2*)(KVb + srcbase + (size_t)(t0 + i) * 1024 + d0 + c4);
    tile[i][c4] = r.s[0]; tile[i][c4 + 1] = r.s[1];
    tile[i][c4 + 2] = r.s[2]; tile[i][c4 + 3] = r.s[3];
  }
  __syncthreads();
  {
    int j = tid >> 3, cc = (tid & 7) * 4;
    union { uint2 u; u16 s[4]; } w;
    w.s[0] = tile[cc][j]; w.s[1] = tile[cc + 1][j];
    w.s[2] = tile[cc + 2][j]; w.s[3] = tile[cc + 3][j];
    *(uint2*)(VTg + (size_t)(vb + d0 + j) * TT + t0 + cc) = w.u;
  }
}

// ---------------- 256x256 8-phase bf16 GEMM (T1+T2+T3+T4+T5) --------------
// (unchanged — refcheck'd at 477 µs total)
template <int MODE>
__global__ __launch_bounds__(512) void gemm256(const u16* __restrict__ A,
                                               const u16* __restrict__ Bt0,
                                               const u16* __restrict__ Bt1,
                                               void* __restrict__ C0,
                                               void* __restrict__ C1,
                                               int M, int N0, int N1, int K, int nbx) {
  __shared__ __align__(16) u16 sh[2][4][8192];  // [buf][A0,A1,B0,B1][128*64]
  const int tid = threadIdx.x;
  const int lane = tid & 63, wave = tid >> 6;
  const int quad = lane >> 4, n16 = lane & 15;
  const int mi = wave >> 2, ni = wave & 3;

  const int nwg = gridDim.x;
  int wg = blockIdx.x;
  wg = (wg & 7) * (nwg >> 3) + (wg >> 3);
  const int bx = wg % nbx, by = wg / nbx;
  const size_t rowbase = (size_t)by * 256;
  const int colbase = bx * 256;

  const u16* Bt = Bt0;
  int bcol = colbase;
  if (MODE == 1 && colbase >= N0) { Bt = Bt1; bcol = colbase - N0; }

  const int c0 = tid, c1 = tid + 512;
  const int r0s = c0 >> 3, ci0 = (c0 & 7) ^ (r0s & 7);
  const int r1s = c1 >> 3, ci1 = (c1 & 7) ^ (r1s & 7);
  const u16* Ag0 = A + (rowbase + r0s) * (size_t)K + ci0 * 8;
  const u16* Ag1 = A + (rowbase + r1s) * (size_t)K + ci1 * 8;
  const u16* Bg0 = Bt + ((size_t)bcol + r0s) * K + ci0 * 8;
  const u16* Bg1 = Bt + ((size_t)bcol + r1s) * K + ci1 * 8;
  const size_t h128K = (size_t)128 * K;

#define STAGE(ob, h, kb) do {                                              \
    if ((h) < 2) {                                                         \
      gl_lds16(Ag0 + (size_t)(h) * h128K + (kb), &sh[ob][h][c0 * 8]);      \
      gl_lds16(Ag1 + (size_t)(h) * h128K + (kb), &sh[ob][h][c1 * 8]);      \
    } else {                                                               \
      gl_lds16(Bg0 + (size_t)((h) - 2) * h128K + (kb), &sh[ob][h][c0 * 8]);\
      gl_lds16(Bg1 + (size_t)((h) - 2) * h128K + (kb), &sh[ob][h][c1 * 8]);\
    } } while (0)

#define LDA_HALF(mh) do {                                                  \
    _Pragma("unroll") for (int m = 0; m < 4; ++m)                          \
      _Pragma("unroll") for (int kk = 0; kk < 2; ++kk) {                   \
        int row_ = ((mh) * 4 + m) * 16 + n16;                              \
        int c_ = row_ * 8 + ((kk * 4 + quad) ^ (n16 & 7));                 \
        af[m][kk] = *(const bf16x8*)&sh[buf][mi][c_ * 8];                  \
      } } while (0)

#define LDB_HALF(nh, BF) do {                                              \
    _Pragma("unroll") for (int n = 0; n < 2; ++n)                          \
      _Pragma("unroll") for (int kk = 0; kk < 2; ++kk) {                   \
        int row_ = (ni & 1) * 64 + ((nh) * 2 + n) * 16 + n16;              \
        int c_ = row_ * 8 + ((kk * 4 + quad) ^ (n16 & 7));                 \
        BF[n][kk] = *(const bf16x8*)&sh[buf][2 + (ni >> 1)][c_ * 8];       \
      } } while (0)

#define DO_QUAD(mh, nh, BF) do {                                           \
    __builtin_amdgcn_s_setprio(1);                                         \
    _Pragma("unroll") for (int m = 0; m < 4; ++m)                          \
      _Pragma("unroll") for (int n = 0; n < 2; ++n)                        \
        _Pragma("unroll") for (int kk = 0; kk < 2; ++kk)                   \
          acc[(mh) * 4 + m][(nh) * 2 + n] =                                \
              __builtin_amdgcn_mfma_f32_16x16x32_bf16(                     \
                  af[m][kk], BF[n][kk], acc[(mh) * 4 + m][(nh) * 2 + n],   \
                  0, 0, 0);                                                \
    __builtin_amdgcn_s_setprio(0);                                         \
  } while (0)

#define FENCE() asm volatile("" ::: "memory")

  f32x4 acc[8][4];
  #pragma unroll
  for (int i = 0; i < 8; ++i)
    #pragma unroll
    for (int j = 0; j < 4; ++j) acc[i][j] = (f32x4){0.f, 0.f, 0.f, 0.f};

  bf16x8 af[4][2], bf0[2][2], bf1[2][2];
  const int nt = K / 64;

  STAGE(0, 0, 0); STAGE(0, 1, 0); STAGE(0, 2, 0); STAGE(0, 3, 0);

  #pragma unroll 2
  for (int t = 0; t < nt; ++t) {
    const int buf = t & 1, ob = buf ^ 1;
    const int kbn = (t + 1) * 64;
    const bool pre = (t + 1 < nt);

    if (pre) {
      STAGE(ob, 0, kbn);
      asm volatile("s_waitcnt vmcnt(2)" ::: "memory");
    } else {
      asm volatile("s_waitcnt vmcnt(0)" ::: "memory");
    }
    __builtin_amdgcn_s_barrier(); FENCE();
    LDA_HALF(0); LDB_HALF(0, bf0);
    DO_QUAD(0, 0, bf0);
    __builtin_amdgcn_s_barrier(); FENCE();

    LDB_HALF(1, bf1);
    if (pre) STAGE(ob, 1, kbn);
    __builtin_amdgcn_s_barrier(); FENCE();
    DO_QUAD(0, 1, bf1);
    __builtin_amdgcn_s_barrier(); FENCE();

    LDA_HALF(1);
    if (pre) STAGE(ob, 2, kbn);
    __builtin_amdgcn_s_barrier(); FENCE();
    DO_QUAD(1, 1, bf1);
    __builtin_amdgcn_s_barrier(); FENCE();

    if (pre) STAGE(ob, 3, kbn);
    __builtin_amdgcn_s_barrier(); FENCE();
    DO_QUAD(1, 0, bf0);
    __builtin_amdgcn_s_barrier(); FENCE();
  }

#undef STAGE
#undef LDA_HALF
#undef LDB_HALF
#undef DO_QUAD
#undef FENCE

  const size_t crow0 = rowbase + (size_t)mi * 128;
  #pragma unroll
  for (int mt = 0; mt < 8; ++mt) {
    #pragma unroll
    for (int r = 0; r < 4; ++r) {
      size_t row = crow0 + mt * 16 + quad * 4 + r;
      #pragma unroll
      for (int nt_ = 0; nt_ < 4; ++nt_) {
        int col = colbase + ni * 64 + nt_ * 16 + n16;
        float v = acc[mt][nt_][r];
        if (MODE == 0) {
          ((float*)C0)[row * (size_t)N0 + col] = v;
        } else {
          if (col < N0) ((u16*)C0)[row * (size_t)N0 + col] = f2bf(v);
          else          ((u16*)C1)[row * (size_t)N1 + (col - N0)] = f2bf(v);
        }
      }
    }
  }
}

// ---------------- flash attention (causal, GQA), no-max softmax ------------
// Round-2: double-buffered K/V staging w/ counted vmcnt (T3/T4-lite), raw
// s_barriers; Vt XOR swizzle (both-sides, rule 21); softmax VALU diet
// (wave-uniform mask hoist + v_cvt_pk_bf16_f32); P-wait lgkmcnt(0)-only +
// sched_barrier (rule 18); setprio on MFMA clusters (T5).
// Round-3: single-pass grid (16,64)=1024 blocks (big-first qt=15-bx) so
// 3 blocks/CU fit (42 KiB LDS) instead of the grid-capped 2; wave-uniform
// skip of fully-masked tiles.
__global__ __launch_bounds__(256) void attn_kernel(const u16* __restrict__ Qm,
                                                   const u16* __restrict__ KVm,
                                                   const u16* __restrict__ VTg,
                                                   u16* __restrict__ Ym) {
  __shared__ u16 Ks[2][32 * 128];
  __shared__ u16 Vt[2][128 * 32];
  __shared__ u16 Pb[4 * 32 * 40];

  const int tid = threadIdx.x;
  const int lane = tid & 63, wave = tid >> 6;
  const int quad = lane >> 4, n16 = lane & 15;
  const int b = blockIdx.y >> 4, h = blockIdx.y & 15;
  const int kvh = h >> 2;
  const int kvbase = b * TT;
  const u16* VTg_ = VTg + (size_t)((b * 4 + kvh) * 128) * TT;

  // K staging: XOR-16 chunk swizzle (conflict-free verified)
  const int krow = tid >> 4, kslot = tid & 15;
  const int kg = (kslot ^ krow) * 8;
  // V staging: rows of 32 u16 = 4 chunks; swizzle ci^((row>>1)&3).
  // LDS dest stays linear (byte = tid*16); source carries the swizzle.
  const int vrow = tid >> 2, vs = tid & 3;
  const int vq8 = (vs ^ ((tid >> 3) & 3)) * 8;

#define STAGEKV(bi, kb) do {                                                          \
    gl_lds16(KVm + (size_t)(kvbase + (kb) + krow) * 1024 + kvh * DD + kg,             \
             &Ks[bi][krow * 128 + kslot * 8]);                                        \
    gl_lds16(KVm + (size_t)(kvbase + (kb) + krow + 16) * 1024 + kvh * DD + kg,        \
             &Ks[bi][(krow + 16) * 128 + kslot * 8]);                                 \
    gl_lds16(VTg_ + (size_t)vrow * TT + (kb) + vq8, &Vt[bi][vrow * 32 + vs * 8]);     \
    gl_lds16(VTg_ + (size_t)(vrow + 64) * TT + (kb) + vq8,                            \
             &Vt[bi][(vrow + 64) * 32 + vs * 8]);                                     \
  } while (0)

  constexpr float SCL = 0.08838834764831843f * 1.4426950408889634f;

  // single pass: big q-tiles dispatched first so small ones fill the tail
  const int qt = 15 - (int)blockIdx.x;
  const int q0 = qt * 128;
  const size_t qrowbase = (size_t)(b * TT + q0);
  const int wq0 = wave * 32;
  const int qmin = q0 + wq0;

  bf16x8 aq[2][4];
  #pragma unroll
  for (int mt = 0; mt < 2; ++mt) {
    const u16* qp = Qm + (qrowbase + wq0 + mt * 16 + n16) * (HH * DD) + h * DD + quad * 8;
    #pragma unroll
    for (int dt = 0; dt < 4; ++dt)
      aq[mt][dt] = *(const bf16x8*)(qp + dt * 32);
  }

  float lrow[2][4];
  f32x4 oacc[2][8];
  #pragma unroll
  for (int mt = 0; mt < 2; ++mt) {
    #pragma unroll
    for (int r = 0; r < 4; ++r) lrow[mt][r] = 0.f;
    #pragma unroll
    for (int i = 0; i < 8; ++i) oacc[mt][i] = (f32x4){0.f, 0.f, 0.f, 0.f};
  }

  const int kend = q0 + 128;
  STAGEKV(0, 0);                       // prologue into buf 0
  for (int kb = 0; kb < kend; kb += 32) {
    const int bi = (kb >> 5) & 1;
    const bool pre = (kb + 32 < kend);
    if (pre) {
      STAGEKV(bi ^ 1, kb + 32);        // prefetch next tile
      asm volatile("s_waitcnt vmcnt(4)" ::: "memory");  // this tile's 4 done
    } else {
      asm volatile("s_waitcnt vmcnt(0)" ::: "memory");  // tail drain
    }
    __builtin_amdgcn_s_barrier();
    asm volatile("" ::: "memory");

    // wave-uniform: skip tiles that are entirely above the diagonal
    if (kb <= qmin + 31) {
      // S = Q K^T : 2 m-tiles x 2 key-halves, K-frags shared across m
      f32x4 sf[2][2];
      #pragma unroll
      for (int half = 0; half < 2; ++half) {
        bf16x8 bk[4];
        #pragma unroll
        for (int dt = 0; dt < 4; ++dt) {
          int slot = (dt * 4 + quad) ^ n16;   // un-swizzle
          bk[dt] = *(const bf16x8*)&Ks[bi][(half * 16 + n16) * 128 + slot * 8];
        }
        __builtin_amdgcn_s_setprio(1);
        #pragma unroll
        for (int mt = 0; mt < 2; ++mt) {
          f32x4 s = (f32x4){0.f, 0.f, 0.f, 0.f};
          #pragma unroll
          for (int dt = 0; dt < 4; ++dt)
            s = __builtin_amdgcn_mfma_f32_16x16x32_bf16(aq[mt][dt], bk[dt], s, 0, 0, 0);
          sf[mt][half] = s;
        }
        __builtin_amdgcn_s_setprio(0);
      }

      // p = exp2(s*scale*log2e); mask only when the tile crosses the diagonal
      u16* pw = &Pb[wave * (32 * 40)];
      const bool needmask = (kb + 31 > qmin);   // wave-uniform
      #pragma unroll
      for (int mt = 0; mt < 2; ++mt) {
        #pragma unroll
        for (int half = 0; half < 2; ++half) {
          const int key = kb + half * 16 + n16;
          float p0 = exp2f(sf[mt][half][0] * SCL);
          float p1 = exp2f(sf[mt][half][1] * SCL);
          float p2 = exp2f(sf[mt][half][2] * SCL);
          float p3 = exp2f(sf[mt][half][3] * SCL);
          if (needmask) {
            const int qp0 = qmin + mt * 16 + quad * 4;
            if (key > qp0)     p0 = 0.f;
            if (key > qp0 + 1) p1 = 0.f;
            if (key > qp0 + 2) p2 = 0.f;
            if (key > qp0 + 3) p3 = 0.f;
          }
          lrow[mt][0] += p0; lrow[mt][1] += p1;
          lrow[mt][2] += p2; lrow[mt][3] += p3;
          unsigned pk01, pk23;
          asm("v_cvt_pk_bf16_f32 %0, %1, %2" : "=v"(pk01) : "v"(p0), "v"(p1));
          asm("v_cvt_pk_bf16_f32 %0, %1, %2" : "=v"(pk23) : "v"(p2), "v"(p3));
          const int pb = (mt * 16 + quad * 4) * 40 + half * 16 + n16;
          pw[pb]       = (u16)pk01;
          pw[pb + 40]  = (u16)(pk01 >> 16);
          pw[pb + 80]  = (u16)pk23;
          pw[pb + 120] = (u16)(pk23 >> 16);
        }
      }
      // drain ds_writes only (NOT vmcnt — prefetch stays in flight)
      asm volatile("s_waitcnt lgkmcnt(0)" ::: "memory");
      __builtin_amdgcn_sched_barrier(0);
      bf16x8 ap0 = *(const bf16x8*)&pw[n16 * 40 + quad * 8];
      bf16x8 ap1 = *(const bf16x8*)&pw[(16 + n16) * 40 + quad * 8];

      // O += P V : V-frags shared across m-tiles (swizzled read)
      __builtin_amdgcn_s_setprio(1);
      #pragma unroll
      for (int dt = 0; dt < 8; ++dt) {
        bf16x8 bv = *(const bf16x8*)&Vt[bi][(dt * 16 + n16) * 32 +
                                           ((quad ^ ((n16 >> 1) & 3)) * 8)];
        oacc[0][dt] = __builtin_amdgcn_mfma_f32_16x16x32_bf16(ap0, bv, oacc[0][dt], 0, 0, 0);
        oacc[1][dt] = __builtin_amdgcn_mfma_f32_16x16x32_bf16(ap1, bv, oacc[1][dt], 0, 0, 0);
      }
      __builtin_amdgcn_s_setprio(0);
    }

    asm volatile("" ::: "memory");
    __builtin_amdgcn_s_barrier();   // all reads of buf bi done before overwrite
    asm volatile("" ::: "memory");
  }

  // epilogue: reduce l across the 16 key-lanes, normalize, store
  float rinv[2][4];
  #pragma unroll
  for (int mt = 0; mt < 2; ++mt)
    #pragma unroll
    for (int r = 0; r < 4; ++r) {
      float v = lrow[mt][r];
      v += __shfl_xor(v, 1, 64);
      v += __shfl_xor(v, 2, 64);
      v += __shfl_xor(v, 4, 64);
      v += __shfl_xor(v, 8, 64);
      rinv[mt][r] = 1.0f / v;
    }
  #pragma unroll
  for (int mt = 0; mt < 2; ++mt)
    #pragma unroll
    for (int dt = 0; dt < 8; ++dt)
      #pragma unroll
      for (int r = 0; r < 4; ++r) {
        size_t row = qrowbase + wq0 + mt * 16 + quad * 4 + r;
        Ym[row * (HH * DD) + h * DD + dt * 16 + n16] = f2bf(oacc[mt][dt][r] * rinv[mt][r]);
      }
#undef STAGEKV
}

// ---------------- launch ----------------
extern "C" void kernel_launch(void* const* d_in, const int* in_sizes, int n_in,
                              void* d_out, int out_size, void* d_ws, size_t ws_size,
                              hipStream_t stream) {
  const float* x  = (const float*)d_in[0];
  const float* Wq = (const float*)d_in[1];
  const float* Wk = (const float*)d_in[2];
  const float* Wv = (const float*)d_in[3];
  const float* Wo = (const float*)d_in[4];
  float* out = (float*)d_out;

  u16* ws   = (u16*)d_ws;
  u16* xb   = ws;                                  // 8192*2048 u16 (32 MiB)
  u16* Wbuf = xb + (size_t)8192 * 2048;            // 2048*2048 u16 (8 MiB)
  u16* Yb   = xb;                                  // alias: xb dead after QKV GEMM

  u16* ob   = (u16*)d_out;
  u16* Qb   = ob;                                                  // 32 MiB
  u16* KVb  = ob + (size_t)8192 * 2048;                            // 16 MiB
  u16* VTg  = ob + (size_t)8192 * 2048 + (size_t)8192 * 1024;      // 8 MiB
  u16* WkvT = VTg + (size_t)16 * 128 * 2048;                       // 4 MiB (1024x2048)

  cvt_f32_bf16<<<16384, 256, 0, stream>>>(x, xb, (4 * 2048 * 2048) / 4);

  transpose_w<<<dim3(64, 64), 256, 0, stream>>>(Wq, Wbuf, 2048, 2048);
  transpose_w<<<dim3(16, 64), 256, 0, stream>>>(Wk, WkvT, 2048, 512);
  transpose_w<<<dim3(16, 64), 256, 0, stream>>>(Wv, WkvT + (size_t)512 * 2048, 2048, 512);

  // fused [Q | KV] = x [Wq | Wk | Wv]   (N = 3072, grid 384)
  gemm256<1><<<384, 512, 0, stream>>>(xb, Wbuf, WkvT, (void*)Qb, (void*)KVb,
                                      8192, 2048, 1024, 2048, 12);

  transpose_v<<<dim3(64, 4, 16), 256, 0, stream>>>(KVb, VTg);

  attn_kernel<<<dim3(16, 64), 256, 0, stream>>>(Qb, KVb, VTg, Yb);

  transpose_w<<<dim3(64, 64), 256, 0, stream>>>(Wo, Wbuf, 2048, 2048);
  gemm256<0><<<256, 512, 0, stream>>>(Yb, Wbuf, nullptr, (void*)out, nullptr,
                                      8192, 2048, 0, 2048, 8);
}

// Round 8
// 576.841 us; speedup vs baseline: 1.0035x; 1.0035x over previous
//
#include <hip/hip_runtime.h>

typedef unsigned short u16;
typedef __attribute__((ext_vector_type(8))) __bf16 bf16x8;
typedef __attribute__((ext_vector_type(4))) float f32x4;

// Problem constants
#define BB 4
#define TT 2048
#define EE 2048
#define HH 16
#define KVH 4
#define DD 128
// KVb: (B*T, 1024): cols [0,512) = K heads, [512,1024) = V heads

static __device__ __forceinline__ u16 f2bf(float f) {
  unsigned int u = __float_as_uint(f);
  u += 0x7fffu + ((u >> 16) & 1u);
  return (u16)(u >> 16);
}

// async global->LDS, 16B per lane. LDS dest is wave-uniform base + lane*16;
// all call sites pass per-lane pointers that are linear in lane with stride 16B.
static __device__ __forceinline__ void gl_lds16(const u16* g, u16* l) {
  __builtin_amdgcn_global_load_lds((__attribute__((address_space(1))) void*)g,
                                   (__attribute__((address_space(3))) void*)l,
                                   16, 0, 0);
}

// ---------------- fp32 -> bf16 convert ----------------
__global__ __launch_bounds__(256) void cvt_f32_bf16(const float* __restrict__ in,
                                                    u16* __restrict__ out, int n4) {
  int i = blockIdx.x * 256 + threadIdx.x;
  if (i >= n4) return;
  float4 v = ((const float4*)in)[i];
  union { uint2 u2; u16 s[4]; } o;
  o.s[0] = f2bf(v.x); o.s[1] = f2bf(v.y); o.s[2] = f2bf(v.z); o.s[3] = f2bf(v.w);
  ((uint2*)out)[i] = o.u2;
}

// ---------------- W (R x C) fp32 -> W^T (C x R) bf16 ----------------
__global__ __launch_bounds__(256) void transpose_w(const float* __restrict__ W,
                                                   u16* __restrict__ Wt, int R, int C) {
  __shared__ float tile[32][33];
  int tx = threadIdx.x & 31, ty = threadIdx.x >> 5;
  int r0 = blockIdx.y * 32, c0 = blockIdx.x * 32;
  #pragma unroll
  for (int i = ty; i < 32; i += 8)
    tile[i][tx] = W[(size_t)(r0 + i) * C + (c0 + tx)];
  __syncthreads();
  #pragma unroll
  for (int i = ty; i < 32; i += 8)
    Wt[(size_t)(c0 + i) * R + (r0 + tx)] = f2bf(tile[tx][i]);
}

// ---------------- V (bf16, token-major) -> VTg (d-major) ----------------
__global__ __launch_bounds__(256) void transpose_v(const u16* __restrict__ KVb,
                                                   u16* __restrict__ VTg) {
  __shared__ u16 tile[32][36];
  const int tid = threadIdx.x;
  const int t0 = blockIdx.x * 32, d0 = blockIdx.y * 32;
  const int z = blockIdx.z;                       // b*4 + kvh
  const int vb = z * 128;
  const size_t srcbase = (size_t)(z >> 2) * TT * 1024 + 512 + (z & 3) * 128;
  {
    int i = tid >> 3, c4 = (tid & 7) * 4;
    union { uint2 u; u16 s[4]; } r;
    r.u = *(const uint2*)(KVb + srcbase + (size_t)(t0 + i) * 1024 + d0 + c4);
    tile[i][c4] = r.s[0]; tile[i][c4 + 1] = r.s[1];
    tile[i][c4 + 2] = r.s[2]; tile[i][c4 + 3] = r.s[3];
  }
  __syncthreads();
  {
    int j = tid >> 3, cc = (tid & 7) * 4;
    union { uint2 u; u16 s[4]; } w;
    w.s[0] = tile[cc][j]; w.s[1] = tile[cc + 1][j];
    w.s[2] = tile[cc + 2][j]; w.s[3] = tile[cc + 3][j];
    *(uint2*)(VTg + (size_t)(vb + d0 + j) * TT + t0 + cc) = w.u;
  }
}

// ---------------- 256x256 8-phase bf16 GEMM (T1+T2+T3+T4+T5) --------------
// (unchanged — refcheck'd at 477 µs total)
template <int MODE>
__global__ __launch_bounds__(512) void gemm256(const u16* __restrict__ A,
                                               const u16* __restrict__ Bt0,
                                               const u16* __restrict__ Bt1,
                                               void* __restrict__ C0,
                                               void* __restrict__ C1,
                                               int M, int N0, int N1, int K, int nbx) {
  __shared__ __align__(16) u16 sh[2][4][8192];  // [buf][A0,A1,B0,B1][128*64]
  const int tid = threadIdx.x;
  const int lane = tid & 63, wave = tid >> 6;
  const int quad = lane >> 4, n16 = lane & 15;
  const int mi = wave >> 2, ni = wave & 3;

  const int nwg = gridDim.x;
  int wg = blockIdx.x;
  wg = (wg & 7) * (nwg >> 3) + (wg >> 3);
  const int bx = wg % nbx, by = wg / nbx;
  const size_t rowbase = (size_t)by * 256;
  const int colbase = bx * 256;

  const u16* Bt = Bt0;
  int bcol = colbase;
  if (MODE == 1 && colbase >= N0) { Bt = Bt1; bcol = colbase - N0; }

  const int c0 = tid, c1 = tid + 512;
  const int r0s = c0 >> 3, ci0 = (c0 & 7) ^ (r0s & 7);
  const int r1s = c1 >> 3, ci1 = (c1 & 7) ^ (r1s & 7);
  const u16* Ag0 = A + (rowbase + r0s) * (size_t)K + ci0 * 8;
  const u16* Ag1 = A + (rowbase + r1s) * (size_t)K + ci1 * 8;
  const u16* Bg0 = Bt + ((size_t)bcol + r0s) * K + ci0 * 8;
  const u16* Bg1 = Bt + ((size_t)bcol + r1s) * K + ci1 * 8;
  const size_t h128K = (size_t)128 * K;

#define STAGE(ob, h, kb) do {                                              \
    if ((h) < 2) {                                                         \
      gl_lds16(Ag0 + (size_t)(h) * h128K + (kb), &sh[ob][h][c0 * 8]);      \
      gl_lds16(Ag1 + (size_t)(h) * h128K + (kb), &sh[ob][h][c1 * 8]);      \
    } else {                                                               \
      gl_lds16(Bg0 + (size_t)((h) - 2) * h128K + (kb), &sh[ob][h][c0 * 8]);\
      gl_lds16(Bg1 + (size_t)((h) - 2) * h128K + (kb), &sh[ob][h][c1 * 8]);\
    } } while (0)

#define LDA_HALF(mh) do {                                                  \
    _Pragma("unroll") for (int m = 0; m < 4; ++m)                          \
      _Pragma("unroll") for (int kk = 0; kk < 2; ++kk) {                   \
        int row_ = ((mh) * 4 + m) * 16 + n16;                              \
        int c_ = row_ * 8 + ((kk * 4 + quad) ^ (n16 & 7));                 \
        af[m][kk] = *(const bf16x8*)&sh[buf][mi][c_ * 8];                  \
      } } while (0)

#define LDB_HALF(nh, BF) do {                                              \
    _Pragma("unroll") for (int n = 0; n < 2; ++n)                          \
      _Pragma("unroll") for (int kk = 0; kk < 2; ++kk) {                   \
        int row_ = (ni & 1) * 64 + ((nh) * 2 + n) * 16 + n16;              \
        int c_ = row_ * 8 + ((kk * 4 + quad) ^ (n16 & 7));                 \
        BF[n][kk] = *(const bf16x8*)&sh[buf][2 + (ni >> 1)][c_ * 8];       \
      } } while (0)

#define DO_QUAD(mh, nh, BF) do {                                           \
    __builtin_amdgcn_s_setprio(1);                                         \
    _Pragma("unroll") for (int m = 0; m < 4; ++m)                          \
      _Pragma("unroll") for (int n = 0; n < 2; ++n)                        \
        _Pragma("unroll") for (int kk = 0; kk < 2; ++kk)                   \
          acc[(mh) * 4 + m][(nh) * 2 + n] =                                \
              __builtin_amdgcn_mfma_f32_16x16x32_bf16(                     \
                  af[m][kk], BF[n][kk], acc[(mh) * 4 + m][(nh) * 2 + n],   \
                  0, 0, 0);                                                \
    __builtin_amdgcn_s_setprio(0);                                         \
  } while (0)

#define FENCE() asm volatile("" ::: "memory")

  f32x4 acc[8][4];
  #pragma unroll
  for (int i = 0; i < 8; ++i)
    #pragma unroll
    for (int j = 0; j < 4; ++j) acc[i][j] = (f32x4){0.f, 0.f, 0.f, 0.f};

  bf16x8 af[4][2], bf0[2][2], bf1[2][2];
  const int nt = K / 64;

  STAGE(0, 0, 0); STAGE(0, 1, 0); STAGE(0, 2, 0); STAGE(0, 3, 0);

  #pragma unroll 2
  for (int t = 0; t < nt; ++t) {
    const int buf = t & 1, ob = buf ^ 1;
    const int kbn = (t + 1) * 64;
    const bool pre = (t + 1 < nt);

    if (pre) {
      STAGE(ob, 0, kbn);
      asm volatile("s_waitcnt vmcnt(2)" ::: "memory");
    } else {
      asm volatile("s_waitcnt vmcnt(0)" ::: "memory");
    }
    __builtin_amdgcn_s_barrier(); FENCE();
    LDA_HALF(0); LDB_HALF(0, bf0);
    DO_QUAD(0, 0, bf0);
    __builtin_amdgcn_s_barrier(); FENCE();

    LDB_HALF(1, bf1);
    if (pre) STAGE(ob, 1, kbn);
    __builtin_amdgcn_s_barrier(); FENCE();
    DO_QUAD(0, 1, bf1);
    __builtin_amdgcn_s_barrier(); FENCE();

    LDA_HALF(1);
    if (pre) STAGE(ob, 2, kbn);
    __builtin_amdgcn_s_barrier(); FENCE();
    DO_QUAD(1, 1, bf1);
    __builtin_amdgcn_s_barrier(); FENCE();

    if (pre) STAGE(ob, 3, kbn);
    __builtin_amdgcn_s_barrier(); FENCE();
    DO_QUAD(1, 0, bf0);
    __builtin_amdgcn_s_barrier(); FENCE();
  }

#undef STAGE
#undef LDA_HALF
#undef LDB_HALF
#undef DO_QUAD
#undef FENCE

  const size_t crow0 = rowbase + (size_t)mi * 128;
  #pragma unroll
  for (int mt = 0; mt < 8; ++mt) {
    #pragma unroll
    for (int r = 0; r < 4; ++r) {
      size_t row = crow0 + mt * 16 + quad * 4 + r;
      #pragma unroll
      for (int nt_ = 0; nt_ < 4; ++nt_) {
        int col = colbase + ni * 64 + nt_ * 16 + n16;
        float v = acc[mt][nt_][r];
        if (MODE == 0) {
          ((float*)C0)[row * (size_t)N0 + col] = v;
        } else {
          if (col < N0) ((u16*)C0)[row * (size_t)N0 + col] = f2bf(v);
          else          ((u16*)C1)[row * (size_t)N1 + (col - N0)] = f2bf(v);
        }
      }
    }
  }
}

// ---------------- flash attention (causal, GQA), no-max softmax ------------
// Balanced 2-pass grid (8,64) — every block does exactly 68 k-tiles
// (qt=bx then 15-bx), 2 blocks/CU homogeneous residency [round-3's single-pass
// split regressed 151->252 via heavy-block tail at ~1 block/CU].
// Body (round-2, counters-validated): double-buffered K/V staging with counted
// vmcnt (T3/T4-lite), raw s_barriers; Vt XOR swizzle both-sides (bank conflicts
// 5.57M->1.06M, now negligible); softmax VALU diet (mask hoist +
// v_cvt_pk_bf16_f32; VALUBusy 51->34); P-wait lgkmcnt(0)-only + sched_barrier
// (rule 18); setprio on MFMA clusters (T5); wave-uniform dead-tile skip.
__global__ __launch_bounds__(256) void attn_kernel(const u16* __restrict__ Qm,
                                                   const u16* __restrict__ KVm,
                                                   const u16* __restrict__ VTg,
                                                   u16* __restrict__ Ym) {
  __shared__ u16 Ks[2][32 * 128];
  __shared__ u16 Vt[2][128 * 32];
  __shared__ u16 Pb[4 * 32 * 40];

  const int tid = threadIdx.x;
  const int lane = tid & 63, wave = tid >> 6;
  const int quad = lane >> 4, n16 = lane & 15;
  const int b = blockIdx.y >> 4, h = blockIdx.y & 15;
  const int kvh = h >> 2;
  const int kvbase = b * TT;
  const u16* VTg_ = VTg + (size_t)((b * 4 + kvh) * 128) * TT;

  // K staging: XOR-16 chunk swizzle (conflict-free verified)
  const int krow = tid >> 4, kslot = tid & 15;
  const int kg = (kslot ^ krow) * 8;
  // V staging: rows of 32 u16 = 4 chunks; swizzle ci^((row>>1)&3).
  // LDS dest stays linear (byte = tid*16); source carries the swizzle.
  const int vrow = tid >> 2, vs = tid & 3;
  const int vq8 = (vs ^ ((tid >> 3) & 3)) * 8;

#define STAGEKV(bi, kb) do {                                                          \
    gl_lds16(KVm + (size_t)(kvbase + (kb) + krow) * 1024 + kvh * DD + kg,             \
             &Ks[bi][krow * 128 + kslot * 8]);                                        \
    gl_lds16(KVm + (size_t)(kvbase + (kb) + krow + 16) * 1024 + kvh * DD + kg,        \
             &Ks[bi][(krow + 16) * 128 + kslot * 8]);                                 \
    gl_lds16(VTg_ + (size_t)vrow * TT + (kb) + vq8, &Vt[bi][vrow * 32 + vs * 8]);     \
    gl_lds16(VTg_ + (size_t)(vrow + 64) * TT + (kb) + vq8,                            \
             &Vt[bi][(vrow + 64) * 32 + vs * 8]);                                     \
  } while (0)

  constexpr float SCL = 0.08838834764831843f * 1.4426950408889634f;

  for (int pass = 0; pass < 2; ++pass) {
    const int qt = pass ? 15 - (int)blockIdx.x : (int)blockIdx.x;
    const int q0 = qt * 128;
    const size_t qrowbase = (size_t)(b * TT + q0);
    const int wq0 = wave * 32;
    const int qmin = q0 + wq0;

    bf16x8 aq[2][4];
    #pragma unroll
    for (int mt = 0; mt < 2; ++mt) {
      const u16* qp = Qm + (qrowbase + wq0 + mt * 16 + n16) * (HH * DD) + h * DD + quad * 8;
      #pragma unroll
      for (int dt = 0; dt < 4; ++dt)
        aq[mt][dt] = *(const bf16x8*)(qp + dt * 32);
    }

    float lrow[2][4];
    f32x4 oacc[2][8];
    #pragma unroll
    for (int mt = 0; mt < 2; ++mt) {
      #pragma unroll
      for (int r = 0; r < 4; ++r) lrow[mt][r] = 0.f;
      #pragma unroll
      for (int i = 0; i < 8; ++i) oacc[mt][i] = (f32x4){0.f, 0.f, 0.f, 0.f};
    }

    const int kend = q0 + 128;
    STAGEKV(0, 0);                       // prologue into buf 0
    for (int kb = 0; kb < kend; kb += 32) {
      const int bi = (kb >> 5) & 1;
      const bool pre = (kb + 32 < kend);
      if (pre) {
        STAGEKV(bi ^ 1, kb + 32);        // prefetch next tile
        asm volatile("s_waitcnt vmcnt(4)" ::: "memory");  // this tile's 4 done
      } else {
        asm volatile("s_waitcnt vmcnt(0)" ::: "memory");  // tail drain
      }
      __builtin_amdgcn_s_barrier();
      asm volatile("" ::: "memory");

      // wave-uniform: skip tiles entirely above this wave's diagonal
      if (kb <= qmin + 31) {
        // S = Q K^T : 2 m-tiles x 2 key-halves, K-frags shared across m
        f32x4 sf[2][2];
        #pragma unroll
        for (int half = 0; half < 2; ++half) {
          bf16x8 bk[4];
          #pragma unroll
          for (int dt = 0; dt < 4; ++dt) {
            int slot = (dt * 4 + quad) ^ n16;   // un-swizzle
            bk[dt] = *(const bf16x8*)&Ks[bi][(half * 16 + n16) * 128 + slot * 8];
          }
          __builtin_amdgcn_s_setprio(1);
          #pragma unroll
          for (int mt = 0; mt < 2; ++mt) {
            f32x4 s = (f32x4){0.f, 0.f, 0.f, 0.f};
            #pragma unroll
            for (int dt = 0; dt < 4; ++dt)
              s = __builtin_amdgcn_mfma_f32_16x16x32_bf16(aq[mt][dt], bk[dt], s, 0, 0, 0);
            sf[mt][half] = s;
          }
          __builtin_amdgcn_s_setprio(0);
        }

        // p = exp2(s*scale*log2e); mask only when the tile crosses the diagonal
        u16* pw = &Pb[wave * (32 * 40)];
        const bool needmask = (kb + 31 > qmin);   // wave-uniform
        #pragma unroll
        for (int mt = 0; mt < 2; ++mt) {
          #pragma unroll
          for (int half = 0; half < 2; ++half) {
            const int key = kb + half * 16 + n16;
            float p0 = exp2f(sf[mt][half][0] * SCL);
            float p1 = exp2f(sf[mt][half][1] * SCL);
            float p2 = exp2f(sf[mt][half][2] * SCL);
            float p3 = exp2f(sf[mt][half][3] * SCL);
            if (needmask) {
              const int qp0 = qmin + mt * 16 + quad * 4;
              if (key > qp0)     p0 = 0.f;
              if (key > qp0 + 1) p1 = 0.f;
              if (key > qp0 + 2) p2 = 0.f;
              if (key > qp0 + 3) p3 = 0.f;
            }
            lrow[mt][0] += p0; lrow[mt][1] += p1;
            lrow[mt][2] += p2; lrow[mt][3] += p3;
            unsigned pk01, pk23;
            asm("v_cvt_pk_bf16_f32 %0, %1, %2" : "=v"(pk01) : "v"(p0), "v"(p1));
            asm("v_cvt_pk_bf16_f32 %0, %1, %2" : "=v"(pk23) : "v"(p2), "v"(p3));
            const int pb = (mt * 16 + quad * 4) * 40 + half * 16 + n16;
            pw[pb]       = (u16)pk01;
            pw[pb + 40]  = (u16)(pk01 >> 16);
            pw[pb + 80]  = (u16)pk23;
            pw[pb + 120] = (u16)(pk23 >> 16);
          }
        }
        // drain ds_writes only (NOT vmcnt — prefetch stays in flight)
        asm volatile("s_waitcnt lgkmcnt(0)" ::: "memory");
        __builtin_amdgcn_sched_barrier(0);
        bf16x8 ap0 = *(const bf16x8*)&pw[n16 * 40 + quad * 8];
        bf16x8 ap1 = *(const bf16x8*)&pw[(16 + n16) * 40 + quad * 8];

        // O += P V : V-frags shared across m-tiles (swizzled read)
        __builtin_amdgcn_s_setprio(1);
        #pragma unroll
        for (int dt = 0; dt < 8; ++dt) {
          bf16x8 bv = *(const bf16x8*)&Vt[bi][(dt * 16 + n16) * 32 +
                                             ((quad ^ ((n16 >> 1) & 3)) * 8)];
          oacc[0][dt] = __builtin_amdgcn_mfma_f32_16x16x32_bf16(ap0, bv, oacc[0][dt], 0, 0, 0);
          oacc[1][dt] = __builtin_amdgcn_mfma_f32_16x16x32_bf16(ap1, bv, oacc[1][dt], 0, 0, 0);
        }
        __builtin_amdgcn_s_setprio(0);
      }

      asm volatile("" ::: "memory");
      __builtin_amdgcn_s_barrier();   // all reads of buf bi done before overwrite
      asm volatile("" ::: "memory");
    }

    // epilogue: reduce l across the 16 key-lanes, normalize, store
    float rinv[2][4];
    #pragma unroll
    for (int mt = 0; mt < 2; ++mt)
      #pragma unroll
      for (int r = 0; r < 4; ++r) {
        float v = lrow[mt][r];
        v += __shfl_xor(v, 1, 64);
        v += __shfl_xor(v, 2, 64);
        v += __shfl_xor(v, 4, 64);
        v += __shfl_xor(v, 8, 64);
        rinv[mt][r] = 1.0f / v;
      }
    #pragma unroll
    for (int mt = 0; mt < 2; ++mt)
      #pragma unroll
      for (int dt = 0; dt < 8; ++dt)
        #pragma unroll
        for (int r = 0; r < 4; ++r) {
          size_t row = qrowbase + wq0 + mt * 16 + quad * 4 + r;
          Ym[row * (HH * DD) + h * DD + dt * 16 + n16] = f2bf(oacc[mt][dt][r] * rinv[mt][r]);
        }
  }
#undef STAGEKV
}

// ---------------- launch ----------------
extern "C" void kernel_launch(void* const* d_in, const int* in_sizes, int n_in,
                              void* d_out, int out_size, void* d_ws, size_t ws_size,
                              hipStream_t stream) {
  const float* x  = (const float*)d_in[0];
  const float* Wq = (const float*)d_in[1];
  const float* Wk = (const float*)d_in[2];
  const float* Wv = (const float*)d_in[3];
  const float* Wo = (const float*)d_in[4];
  float* out = (float*)d_out;

  u16* ws   = (u16*)d_ws;
  u16* xb   = ws;                                  // 8192*2048 u16 (32 MiB)
  u16* Wbuf = xb + (size_t)8192 * 2048;            // 2048*2048 u16 (8 MiB)
  u16* Yb   = xb;                                  // alias: xb dead after QKV GEMM

  u16* ob   = (u16*)d_out;
  u16* Qb   = ob;                                                  // 32 MiB
  u16* KVb  = ob + (size_t)8192 * 2048;                            // 16 MiB
  u16* VTg  = ob + (size_t)8192 * 2048 + (size_t)8192 * 1024;      // 8 MiB
  u16* WkvT = VTg + (size_t)16 * 128 * 2048;                       // 4 MiB (1024x2048)

  cvt_f32_bf16<<<16384, 256, 0, stream>>>(x, xb, (4 * 2048 * 2048) / 4);

  transpose_w<<<dim3(64, 64), 256, 0, stream>>>(Wq, Wbuf, 2048, 2048);
  transpose_w<<<dim3(16, 64), 256, 0, stream>>>(Wk, WkvT, 2048, 512);
  transpose_w<<<dim3(16, 64), 256, 0, stream>>>(Wv, WkvT + (size_t)512 * 2048, 2048, 512);

  // fused [Q | KV] = x [Wq | Wk | Wv]   (N = 3072, grid 384)
  gemm256<1><<<384, 512, 0, stream>>>(xb, Wbuf, WkvT, (void*)Qb, (void*)KVb,
                                      8192, 2048, 1024, 2048, 12);

  transpose_v<<<dim3(64, 4, 16), 256, 0, stream>>>(KVb, VTg);

  attn_kernel<<<dim3(8, 64), 256, 0, stream>>>(Qb, KVb, VTg, Yb);

  transpose_w<<<dim3(64, 64), 256, 0, stream>>>(Wo, Wbuf, 2048, 2048);
  gemm256<0><<<256, 512, 0, stream>>>(Yb, Wbuf, nullptr, (void*)out, nullptr,
                                      8192, 2048, 0, 2048, 8);
}

// Round 9
// 549.419 us; speedup vs baseline: 1.0535x; 1.0499x over previous
//
#include <hip/hip_runtime.h>

typedef unsigned short u16;
typedef __attribute__((ext_vector_type(8))) __bf16 bf16x8;
typedef __attribute__((ext_vector_type(4))) float f32x4;

// Problem constants
#define BB 4
#define TT 2048
#define EE 2048
#define HH 16
#define KVH 4
#define DD 128
// KVb: (B*T, 1024): cols [0,512) = K heads, [512,1024) = V heads

static __device__ __forceinline__ u16 f2bf(float f) {
  unsigned int u = __float_as_uint(f);
  u += 0x7fffu + ((u >> 16) & 1u);
  return (u16)(u >> 16);
}

// async global->LDS, 16B per lane. LDS dest is wave-uniform base + lane*16;
// all call sites pass per-lane pointers that are linear in lane with stride 16B.
static __device__ __forceinline__ void gl_lds16(const u16* g, u16* l) {
  __builtin_amdgcn_global_load_lds((__attribute__((address_space(1))) void*)g,
                                   (__attribute__((address_space(3))) void*)l,
                                   16, 0, 0);
}

// ---------------- fp32 -> bf16 convert ----------------
__global__ __launch_bounds__(256) void cvt_f32_bf16(const float* __restrict__ in,
                                                    u16* __restrict__ out, int n4) {
  int i = blockIdx.x * 256 + threadIdx.x;
  if (i >= n4) return;
  float4 v = ((const float4*)in)[i];
  union { uint2 u2; u16 s[4]; } o;
  o.s[0] = f2bf(v.x); o.s[1] = f2bf(v.y); o.s[2] = f2bf(v.z); o.s[3] = f2bf(v.w);
  ((uint2*)out)[i] = o.u2;
}

// ---------------- W (R x C) fp32 -> W^T (C x R) bf16 ----------------
__global__ __launch_bounds__(256) void transpose_w(const float* __restrict__ W,
                                                   u16* __restrict__ Wt, int R, int C) {
  __shared__ float tile[32][33];
  int tx = threadIdx.x & 31, ty = threadIdx.x >> 5;
  int r0 = blockIdx.y * 32, c0 = blockIdx.x * 32;
  #pragma unroll
  for (int i = ty; i < 32; i += 8)
    tile[i][tx] = W[(size_t)(r0 + i) * C + (c0 + tx)];
  __syncthreads();
  #pragma unroll
  for (int i = ty; i < 32; i += 8)
    Wt[(size_t)(c0 + i) * R + (r0 + tx)] = f2bf(tile[tx][i]);
}

// ---------------- V (bf16, token-major) -> VTg (d-major) ----------------
__global__ __launch_bounds__(256) void transpose_v(const u16* __restrict__ KVb,
                                                   u16* __restrict__ VTg) {
  __shared__ u16 tile[32][36];
  const int tid = threadIdx.x;
  const int t0 = blockIdx.x * 32, d0 = blockIdx.y * 32;
  const int z = blockIdx.z;                       // b*4 + kvh
  const int vb = z * 128;
  const size_t srcbase = (size_t)(z >> 2) * TT * 1024 + 512 + (z & 3) * 128;
  {
    int i = tid >> 3, c4 = (tid & 7) * 4;
    union { uint2 u; u16 s[4]; } r;
    r.u = *(const uint2*)(KVb + srcbase + (size_t)(t0 + i) * 1024 + d0 + c4);
    tile[i][c4] = r.s[0]; tile[i][c4 + 1] = r.s[1];
    tile[i][c4 + 2] = r.s[2]; tile[i][c4 + 3] = r.s[3];
  }
  __syncthreads();
  {
    int j = tid >> 3, cc = (tid & 7) * 4;
    union { uint2 u; u16 s[4]; } w;
    w.s[0] = tile[cc][j]; w.s[1] = tile[cc + 1][j];
    w.s[2] = tile[cc + 2][j]; w.s[3] = tile[cc + 3][j];
    *(uint2*)(VTg + (size_t)(vb + d0 + j) * TT + t0 + cc) = w.u;
  }
}

// ---------------- 256x256 8-phase bf16 GEMM (T1+T2+T3+T4+T5) --------------
// (unchanged — refcheck'd)
template <int MODE>
__global__ __launch_bounds__(512) void gemm256(const u16* __restrict__ A,
                                               const u16* __restrict__ Bt0,
                                               const u16* __restrict__ Bt1,
                                               void* __restrict__ C0,
                                               void* __restrict__ C1,
                                               int M, int N0, int N1, int K, int nbx) {
  __shared__ __align__(16) u16 sh[2][4][8192];  // [buf][A0,A1,B0,B1][128*64]
  const int tid = threadIdx.x;
  const int lane = tid & 63, wave = tid >> 6;
  const int quad = lane >> 4, n16 = lane & 15;
  const int mi = wave >> 2, ni = wave & 3;

  const int nwg = gridDim.x;
  int wg = blockIdx.x;
  wg = (wg & 7) * (nwg >> 3) + (wg >> 3);
  const int bx = wg % nbx, by = wg / nbx;
  const size_t rowbase = (size_t)by * 256;
  const int colbase = bx * 256;

  const u16* Bt = Bt0;
  int bcol = colbase;
  if (MODE == 1 && colbase >= N0) { Bt = Bt1; bcol = colbase - N0; }

  const int c0 = tid, c1 = tid + 512;
  const int r0s = c0 >> 3, ci0 = (c0 & 7) ^ (r0s & 7);
  const int r1s = c1 >> 3, ci1 = (c1 & 7) ^ (r1s & 7);
  const u16* Ag0 = A + (rowbase + r0s) * (size_t)K + ci0 * 8;
  const u16* Ag1 = A + (rowbase + r1s) * (size_t)K + ci1 * 8;
  const u16* Bg0 = Bt + ((size_t)bcol + r0s) * K + ci0 * 8;
  const u16* Bg1 = Bt + ((size_t)bcol + r1s) * K + ci1 * 8;
  const size_t h128K = (size_t)128 * K;

#define STAGE(ob, h, kb) do {                                              \
    if ((h) < 2) {                                                         \
      gl_lds16(Ag0 + (size_t)(h) * h128K + (kb), &sh[ob][h][c0 * 8]);      \
      gl_lds16(Ag1 + (size_t)(h) * h128K + (kb), &sh[ob][h][c1 * 8]);      \
    } else {                                                               \
      gl_lds16(Bg0 + (size_t)((h) - 2) * h128K + (kb), &sh[ob][h][c0 * 8]);\
      gl_lds16(Bg1 + (size_t)((h) - 2) * h128K + (kb), &sh[ob][h][c1 * 8]);\
    } } while (0)

#define LDA_HALF(mh) do {                                                  \
    _Pragma("unroll") for (int m = 0; m < 4; ++m)                          \
      _Pragma("unroll") for (int kk = 0; kk < 2; ++kk) {                   \
        int row_ = ((mh) * 4 + m) * 16 + n16;                              \
        int c_ = row_ * 8 + ((kk * 4 + quad) ^ (n16 & 7));                 \
        af[m][kk] = *(const bf16x8*)&sh[buf][mi][c_ * 8];                  \
      } } while (0)

#define LDB_HALF(nh, BF) do {                                              \
    _Pragma("unroll") for (int n = 0; n < 2; ++n)                          \
      _Pragma("unroll") for (int kk = 0; kk < 2; ++kk) {                   \
        int row_ = (ni & 1) * 64 + ((nh) * 2 + n) * 16 + n16;              \
        int c_ = row_ * 8 + ((kk * 4 + quad) ^ (n16 & 7));                 \
        BF[n][kk] = *(const bf16x8*)&sh[buf][2 + (ni >> 1)][c_ * 8];       \
      } } while (0)

#define DO_QUAD(mh, nh, BF) do {                                           \
    __builtin_amdgcn_s_setprio(1);                                         \
    _Pragma("unroll") for (int m = 0; m < 4; ++m)                          \
      _Pragma("unroll") for (int n = 0; n < 2; ++n)                        \
        _Pragma("unroll") for (int kk = 0; kk < 2; ++kk)                   \
          acc[(mh) * 4 + m][(nh) * 2 + n] =                                \
              __builtin_amdgcn_mfma_f32_16x16x32_bf16(                     \
                  af[m][kk], BF[n][kk], acc[(mh) * 4 + m][(nh) * 2 + n],   \
                  0, 0, 0);                                                \
    __builtin_amdgcn_s_setprio(0);                                         \
  } while (0)

#define FENCE() asm volatile("" ::: "memory")

  f32x4 acc[8][4];
  #pragma unroll
  for (int i = 0; i < 8; ++i)
    #pragma unroll
    for (int j = 0; j < 4; ++j) acc[i][j] = (f32x4){0.f, 0.f, 0.f, 0.f};

  bf16x8 af[4][2], bf0[2][2], bf1[2][2];
  const int nt = K / 64;

  STAGE(0, 0, 0); STAGE(0, 1, 0); STAGE(0, 2, 0); STAGE(0, 3, 0);

  #pragma unroll 2
  for (int t = 0; t < nt; ++t) {
    const int buf = t & 1, ob = buf ^ 1;
    const int kbn = (t + 1) * 64;
    const bool pre = (t + 1 < nt);

    if (pre) {
      STAGE(ob, 0, kbn);
      asm volatile("s_waitcnt vmcnt(2)" ::: "memory");
    } else {
      asm volatile("s_waitcnt vmcnt(0)" ::: "memory");
    }
    __builtin_amdgcn_s_barrier(); FENCE();
    LDA_HALF(0); LDB_HALF(0, bf0);
    DO_QUAD(0, 0, bf0);
    __builtin_amdgcn_s_barrier(); FENCE();

    LDB_HALF(1, bf1);
    if (pre) STAGE(ob, 1, kbn);
    __builtin_amdgcn_s_barrier(); FENCE();
    DO_QUAD(0, 1, bf1);
    __builtin_amdgcn_s_barrier(); FENCE();

    LDA_HALF(1);
    if (pre) STAGE(ob, 2, kbn);
    __builtin_amdgcn_s_barrier(); FENCE();
    DO_QUAD(1, 1, bf1);
    __builtin_amdgcn_s_barrier(); FENCE();

    if (pre) STAGE(ob, 3, kbn);
    __builtin_amdgcn_s_barrier(); FENCE();
    DO_QUAD(1, 0, bf0);
    __builtin_amdgcn_s_barrier(); FENCE();
  }

#undef STAGE
#undef LDA_HALF
#undef LDB_HALF
#undef DO_QUAD
#undef FENCE

  const size_t crow0 = rowbase + (size_t)mi * 128;
  #pragma unroll
  for (int mt = 0; mt < 8; ++mt) {
    #pragma unroll
    for (int r = 0; r < 4; ++r) {
      size_t row = crow0 + mt * 16 + quad * 4 + r;
      #pragma unroll
      for (int nt_ = 0; nt_ < 4; ++nt_) {
        int col = colbase + ni * 64 + nt_ * 16 + n16;
        float v = acc[mt][nt_][r];
        if (MODE == 0) {
          ((float*)C0)[row * (size_t)N0 + col] = v;
        } else {
          if (col < N0) ((u16*)C0)[row * (size_t)N0 + col] = f2bf(v);
          else          ((u16*)C1)[row * (size_t)N1 + (col - N0)] = f2bf(v);
        }
      }
    }
  }
}

// ---------------- flash attention (causal, GQA), no-max softmax ------------
// Round-9: REVERT to the round-1 sync structure (measured 151 µs @ 20% occ):
// single-buffer Ks/Vt, __syncthreads() pair per tile, s_waitcnt(0) P-wait,
// no setprio, LDS 26624. [Rounds 3+8 proved the dbuf/raw-barrier/counted-vmcnt
// body costs ~100 µs regardless of grid: 252 & 247 µs @ ~11.7% occ.]
// Kept (sync-independent, refcheck'd twice, counter-validated):
//  - Vt XOR swizzle both-sides (bank conflicts 5.57M -> 1.06M)
//  - softmax VALU diet (wave-uniform mask hoist + v_cvt_pk_bf16_f32)
//  - wave-uniform dead-tile skip (barriers outside the branch)
__global__ __launch_bounds__(256) void attn_kernel(const u16* __restrict__ Qm,
                                                   const u16* __restrict__ KVm,
                                                   const u16* __restrict__ VTg,
                                                   u16* __restrict__ Ym) {
  __shared__ u16 Ks[32 * 128];
  __shared__ u16 Vt[128 * 32];
  __shared__ u16 Pb[4 * 32 * 40];

  const int tid = threadIdx.x;
  const int lane = tid & 63, wave = tid >> 6;
  const int quad = lane >> 4, n16 = lane & 15;
  const int b = blockIdx.y >> 4, h = blockIdx.y & 15;
  const int kvh = h >> 2;
  const int kvbase = b * TT;
  const u16* VTg_ = VTg + (size_t)((b * 4 + kvh) * 128) * TT;

  // K staging: XOR-16 chunk swizzle (conflict-free verified)
  const int krow = tid >> 4, kslot = tid & 15;
  const int kg = (kslot ^ krow) * 8;
  u16* Ksd0 = &Ks[krow * 128 + kslot * 8];      // byte = tid*16 (linear dest)
  u16* Ksd1 = &Ks[(krow + 16) * 128 + kslot * 8];
  // V staging: swizzle ci^((row>>1)&3); linear LDS dest, source carries swizzle.
  const int vrow = tid >> 2, vs = tid & 3;
  const int vq8 = (vs ^ ((tid >> 3) & 3)) * 8;
  u16* Vtd0 = &Vt[vrow * 32 + vs * 8];
  u16* Vtd1 = &Vt[(vrow + 64) * 32 + vs * 8];

  constexpr float SCL = 0.08838834764831843f * 1.4426950408889634f;

  for (int pass = 0; pass < 2; ++pass) {
    const int qt = pass ? 15 - (int)blockIdx.x : (int)blockIdx.x;
    const int q0 = qt * 128;
    const size_t qrowbase = (size_t)(b * TT + q0);
    const int wq0 = wave * 32;
    const int qmin = q0 + wq0;

    bf16x8 aq[2][4];
    #pragma unroll
    for (int mt = 0; mt < 2; ++mt) {
      const u16* qp = Qm + (qrowbase + wq0 + mt * 16 + n16) * (HH * DD) + h * DD + quad * 8;
      #pragma unroll
      for (int dt = 0; dt < 4; ++dt)
        aq[mt][dt] = *(const bf16x8*)(qp + dt * 32);
    }

    float lrow[2][4];
    f32x4 oacc[2][8];
    #pragma unroll
    for (int mt = 0; mt < 2; ++mt) {
      #pragma unroll
      for (int r = 0; r < 4; ++r) lrow[mt][r] = 0.f;
      #pragma unroll
      for (int i = 0; i < 8; ++i) oacc[mt][i] = (f32x4){0.f, 0.f, 0.f, 0.f};
    }

    const int kend = q0 + 128;
    for (int kb = 0; kb < kend; kb += 32) {
      __syncthreads();
      gl_lds16(KVm + (size_t)(kvbase + kb + krow) * 1024 + kvh * DD + kg, Ksd0);
      gl_lds16(KVm + (size_t)(kvbase + kb + krow + 16) * 1024 + kvh * DD + kg, Ksd1);
      gl_lds16(VTg_ + (size_t)vrow * TT + kb + vq8, Vtd0);
      gl_lds16(VTg_ + (size_t)(vrow + 64) * TT + kb + vq8, Vtd1);
      __syncthreads();

      // wave-uniform: skip tiles entirely above this wave's diagonal
      if (kb <= qmin + 31) {
        // S = Q K^T : 2 m-tiles x 2 key-halves, K-frags shared across m
        f32x4 sf[2][2];
        #pragma unroll
        for (int half = 0; half < 2; ++half) {
          bf16x8 bk[4];
          #pragma unroll
          for (int dt = 0; dt < 4; ++dt) {
            int slot = (dt * 4 + quad) ^ n16;   // un-swizzle
            bk[dt] = *(const bf16x8*)&Ks[(half * 16 + n16) * 128 + slot * 8];
          }
          #pragma unroll
          for (int mt = 0; mt < 2; ++mt) {
            f32x4 s = (f32x4){0.f, 0.f, 0.f, 0.f};
            #pragma unroll
            for (int dt = 0; dt < 4; ++dt)
              s = __builtin_amdgcn_mfma_f32_16x16x32_bf16(aq[mt][dt], bk[dt], s, 0, 0, 0);
            sf[mt][half] = s;
          }
        }

        // p = exp2(s*scale*log2e); mask only when the tile crosses the diagonal
        u16* pw = &Pb[wave * (32 * 40)];
        const bool needmask = (kb + 31 > qmin);   // wave-uniform
        #pragma unroll
        for (int mt = 0; mt < 2; ++mt) {
          #pragma unroll
          for (int half = 0; half < 2; ++half) {
            const int key = kb + half * 16 + n16;
            float p0 = exp2f(sf[mt][half][0] * SCL);
            float p1 = exp2f(sf[mt][half][1] * SCL);
            float p2 = exp2f(sf[mt][half][2] * SCL);
            float p3 = exp2f(sf[mt][half][3] * SCL);
            if (needmask) {
              const int qp0 = qmin + mt * 16 + quad * 4;
              if (key > qp0)     p0 = 0.f;
              if (key > qp0 + 1) p1 = 0.f;
              if (key > qp0 + 2) p2 = 0.f;
              if (key > qp0 + 3) p3 = 0.f;
            }
            lrow[mt][0] += p0; lrow[mt][1] += p1;
            lrow[mt][2] += p2; lrow[mt][3] += p3;
            unsigned pk01, pk23;
            asm("v_cvt_pk_bf16_f32 %0, %1, %2" : "=v"(pk01) : "v"(p0), "v"(p1));
            asm("v_cvt_pk_bf16_f32 %0, %1, %2" : "=v"(pk23) : "v"(p2), "v"(p3));
            const int pb = (mt * 16 + quad * 4) * 40 + half * 16 + n16;
            pw[pb]       = (u16)pk01;
            pw[pb + 40]  = (u16)(pk01 >> 16);
            pw[pb + 80]  = (u16)pk23;
            pw[pb + 120] = (u16)(pk23 >> 16);
          }
        }
        // drain ds_writes before same-wave cross-lane read (round-1-proven wait)
        __builtin_amdgcn_s_waitcnt(0);
        bf16x8 ap0 = *(const bf16x8*)&pw[n16 * 40 + quad * 8];
        bf16x8 ap1 = *(const bf16x8*)&pw[(16 + n16) * 40 + quad * 8];

        // O += P V : V-frags shared across m-tiles (swizzled read)
        #pragma unroll
        for (int dt = 0; dt < 8; ++dt) {
          bf16x8 bv = *(const bf16x8*)&Vt[(dt * 16 + n16) * 32 +
                                          ((quad ^ ((n16 >> 1) & 3)) * 8)];
          oacc[0][dt] = __builtin_amdgcn_mfma_f32_16x16x32_bf16(ap0, bv, oacc[0][dt], 0, 0, 0);
          oacc[1][dt] = __builtin_amdgcn_mfma_f32_16x16x32_bf16(ap1, bv, oacc[1][dt], 0, 0, 0);
        }
      }
    }

    // epilogue: reduce l across the 16 key-lanes, normalize, store
    float rinv[2][4];
    #pragma unroll
    for (int mt = 0; mt < 2; ++mt)
      #pragma unroll
      for (int r = 0; r < 4; ++r) {
        float v = lrow[mt][r];
        v += __shfl_xor(v, 1, 64);
        v += __shfl_xor(v, 2, 64);
        v += __shfl_xor(v, 4, 64);
        v += __shfl_xor(v, 8, 64);
        rinv[mt][r] = 1.0f / v;
      }
    #pragma unroll
    for (int mt = 0; mt < 2; ++mt)
      #pragma unroll
      for (int dt = 0; dt < 8; ++dt)
        #pragma unroll
        for (int r = 0; r < 4; ++r) {
          size_t row = qrowbase + wq0 + mt * 16 + quad * 4 + r;
          Ym[row * (HH * DD) + h * DD + dt * 16 + n16] = f2bf(oacc[mt][dt][r] * rinv[mt][r]);
        }
  }
}

// ---------------- launch ----------------
extern "C" void kernel_launch(void* const* d_in, const int* in_sizes, int n_in,
                              void* d_out, int out_size, void* d_ws, size_t ws_size,
                              hipStream_t stream) {
  const float* x  = (const float*)d_in[0];
  const float* Wq = (const float*)d_in[1];
  const float* Wk = (const float*)d_in[2];
  const float* Wv = (const float*)d_in[3];
  const float* Wo = (const float*)d_in[4];
  float* out = (float*)d_out;

  u16* ws   = (u16*)d_ws;
  u16* xb   = ws;                                  // 8192*2048 u16 (32 MiB)
  u16* Wbuf = xb + (size_t)8192 * 2048;            // 2048*2048 u16 (8 MiB)
  u16* Yb   = xb;                                  // alias: xb dead after QKV GEMM

  u16* ob   = (u16*)d_out;
  u16* Qb   = ob;                                                  // 32 MiB
  u16* KVb  = ob + (size_t)8192 * 2048;                            // 16 MiB
  u16* VTg  = ob + (size_t)8192 * 2048 + (size_t)8192 * 1024;      // 8 MiB
  u16* WkvT = VTg + (size_t)16 * 128 * 2048;                       // 4 MiB (1024x2048)

  cvt_f32_bf16<<<16384, 256, 0, stream>>>(x, xb, (4 * 2048 * 2048) / 4);

  transpose_w<<<dim3(64, 64), 256, 0, stream>>>(Wq, Wbuf, 2048, 2048);
  transpose_w<<<dim3(16, 64), 256, 0, stream>>>(Wk, WkvT, 2048, 512);
  transpose_w<<<dim3(16, 64), 256, 0, stream>>>(Wv, WkvT + (size_t)512 * 2048, 2048, 512);

  // fused [Q | KV] = x [Wq | Wk | Wv]   (N = 3072, grid 384)
  gemm256<1><<<384, 512, 0, stream>>>(xb, Wbuf, WkvT, (void*)Qb, (void*)KVb,
                                      8192, 2048, 1024, 2048, 12);

  transpose_v<<<dim3(64, 4, 16), 256, 0, stream>>>(KVb, VTg);

  attn_kernel<<<dim3(8, 64), 256, 0, stream>>>(Qb, KVb, VTg, Yb);

  transpose_w<<<dim3(64, 64), 256, 0, stream>>>(Wo, Wbuf, 2048, 2048);
  gemm256<0><<<256, 512, 0, stream>>>(Yb, Wbuf, nullptr, (void*)out, nullptr,
                                      8192, 2048, 0, 2048, 8);
}

// Round 10
// 475.611 us; speedup vs baseline: 1.2170x; 1.1552x over previous
//
#include <hip/hip_runtime.h>

typedef unsigned short u16;
typedef __attribute__((ext_vector_type(8))) __bf16 bf16x8;
typedef __attribute__((ext_vector_type(4))) float f32x4;

// Problem constants
#define BB 4
#define TT 2048
#define EE 2048
#define HH 16
#define KVH 4
#define DD 128
// KVb: (B*T, 1024): cols [0,512) = K heads, [512,1024) = V heads

static __device__ __forceinline__ u16 f2bf(float f) {
  unsigned int u = __float_as_uint(f);
  u += 0x7fffu + ((u >> 16) & 1u);
  return (u16)(u >> 16);
}

// async global->LDS, 16B per lane. LDS dest is wave-uniform base + lane*16;
// all call sites pass per-lane pointers that are linear in lane with stride 16B.
static __device__ __forceinline__ void gl_lds16(const u16* g, u16* l) {
  __builtin_amdgcn_global_load_lds((__attribute__((address_space(1))) void*)g,
                                   (__attribute__((address_space(3))) void*)l,
                                   16, 0, 0);
}

// ---------------- fp32 -> bf16 convert ----------------
__global__ __launch_bounds__(256) void cvt_f32_bf16(const float* __restrict__ in,
                                                    u16* __restrict__ out, int n4) {
  int i = blockIdx.x * 256 + threadIdx.x;
  if (i >= n4) return;
  float4 v = ((const float4*)in)[i];
  union { uint2 u2; u16 s[4]; } o;
  o.s[0] = f2bf(v.x); o.s[1] = f2bf(v.y); o.s[2] = f2bf(v.z); o.s[3] = f2bf(v.w);
  ((uint2*)out)[i] = o.u2;
}

// ---------------- W (R x C) fp32 -> W^T (C x R) bf16 ----------------
__global__ __launch_bounds__(256) void transpose_w(const float* __restrict__ W,
                                                   u16* __restrict__ Wt, int R, int C) {
  __shared__ float tile[32][33];
  int tx = threadIdx.x & 31, ty = threadIdx.x >> 5;
  int r0 = blockIdx.y * 32, c0 = blockIdx.x * 32;
  #pragma unroll
  for (int i = ty; i < 32; i += 8)
    tile[i][tx] = W[(size_t)(r0 + i) * C + (c0 + tx)];
  __syncthreads();
  #pragma unroll
  for (int i = ty; i < 32; i += 8)
    Wt[(size_t)(c0 + i) * R + (r0 + tx)] = f2bf(tile[tx][i]);
}

// ---------------- V (bf16, token-major) -> VTg (d-major) ----------------
__global__ __launch_bounds__(256) void transpose_v(const u16* __restrict__ KVb,
                                                   u16* __restrict__ VTg) {
  __shared__ u16 tile[32][36];
  const int tid = threadIdx.x;
  const int t0 = blockIdx.x * 32, d0 = blockIdx.y * 32;
  const int z = blockIdx.z;                       // b*4 + kvh
  const int vb = z * 128;
  const size_t srcbase = (size_t)(z >> 2) * TT * 1024 + 512 + (z & 3) * 128;
  {
    int i = tid >> 3, c4 = (tid & 7) * 4;
    union { uint2 u; u16 s[4]; } r;
    r.u = *(const uint2*)(KVb + srcbase + (size_t)(t0 + i) * 1024 + d0 + c4);
    tile[i][c4] = r.s[0]; tile[i][c4 + 1] = r.s[1];
    tile[i][c4 + 2] = r.s[2]; tile[i][c4 + 3] = r.s[3];
  }
  __syncthreads();
  {
    int j = tid >> 3, cc = (tid & 7) * 4;
    union { uint2 u; u16 s[4]; } w;
    w.s[0] = tile[cc][j]; w.s[1] = tile[cc + 1][j];
    w.s[2] = tile[cc + 2][j]; w.s[3] = tile[cc + 3][j];
    *(uint2*)(VTg + (size_t)(vb + d0 + j) * TT + t0 + cc) = w.u;
  }
}

// ---------------- 256x256 8-phase bf16 GEMM (T1+T2+T3+T4+T5) --------------
// (unchanged — refcheck'd)
template <int MODE>
__global__ __launch_bounds__(512) void gemm256(const u16* __restrict__ A,
                                               const u16* __restrict__ Bt0,
                                               const u16* __restrict__ Bt1,
                                               void* __restrict__ C0,
                                               void* __restrict__ C1,
                                               int M, int N0, int N1, int K, int nbx) {
  __shared__ __align__(16) u16 sh[2][4][8192];  // [buf][A0,A1,B0,B1][128*64]
  const int tid = threadIdx.x;
  const int lane = tid & 63, wave = tid >> 6;
  const int quad = lane >> 4, n16 = lane & 15;
  const int mi = wave >> 2, ni = wave & 3;

  const int nwg = gridDim.x;
  int wg = blockIdx.x;
  wg = (wg & 7) * (nwg >> 3) + (wg >> 3);
  const int bx = wg % nbx, by = wg / nbx;
  const size_t rowbase = (size_t)by * 256;
  const int colbase = bx * 256;

  const u16* Bt = Bt0;
  int bcol = colbase;
  if (MODE == 1 && colbase >= N0) { Bt = Bt1; bcol = colbase - N0; }

  const int c0 = tid, c1 = tid + 512;
  const int r0s = c0 >> 3, ci0 = (c0 & 7) ^ (r0s & 7);
  const int r1s = c1 >> 3, ci1 = (c1 & 7) ^ (r1s & 7);
  const u16* Ag0 = A + (rowbase + r0s) * (size_t)K + ci0 * 8;
  const u16* Ag1 = A + (rowbase + r1s) * (size_t)K + ci1 * 8;
  const u16* Bg0 = Bt + ((size_t)bcol + r0s) * K + ci0 * 8;
  const u16* Bg1 = Bt + ((size_t)bcol + r1s) * K + ci1 * 8;
  const size_t h128K = (size_t)128 * K;

#define STAGE(ob, h, kb) do {                                              \
    if ((h) < 2) {                                                         \
      gl_lds16(Ag0 + (size_t)(h) * h128K + (kb), &sh[ob][h][c0 * 8]);      \
      gl_lds16(Ag1 + (size_t)(h) * h128K + (kb), &sh[ob][h][c1 * 8]);      \
    } else {                                                               \
      gl_lds16(Bg0 + (size_t)((h) - 2) * h128K + (kb), &sh[ob][h][c0 * 8]);\
      gl_lds16(Bg1 + (size_t)((h) - 2) * h128K + (kb), &sh[ob][h][c1 * 8]);\
    } } while (0)

#define LDA_HALF(mh) do {                                                  \
    _Pragma("unroll") for (int m = 0; m < 4; ++m)                          \
      _Pragma("unroll") for (int kk = 0; kk < 2; ++kk) {                   \
        int row_ = ((mh) * 4 + m) * 16 + n16;                              \
        int c_ = row_ * 8 + ((kk * 4 + quad) ^ (n16 & 7));                 \
        af[m][kk] = *(const bf16x8*)&sh[buf][mi][c_ * 8];                  \
      } } while (0)

#define LDB_HALF(nh, BF) do {                                              \
    _Pragma("unroll") for (int n = 0; n < 2; ++n)                          \
      _Pragma("unroll") for (int kk = 0; kk < 2; ++kk) {                   \
        int row_ = (ni & 1) * 64 + ((nh) * 2 + n) * 16 + n16;              \
        int c_ = row_ * 8 + ((kk * 4 + quad) ^ (n16 & 7));                 \
        BF[n][kk] = *(const bf16x8*)&sh[buf][2 + (ni >> 1)][c_ * 8];       \
      } } while (0)

#define DO_QUAD(mh, nh, BF) do {                                           \
    __builtin_amdgcn_s_setprio(1);                                         \
    _Pragma("unroll") for (int m = 0; m < 4; ++m)                          \
      _Pragma("unroll") for (int n = 0; n < 2; ++n)                        \
        _Pragma("unroll") for (int kk = 0; kk < 2; ++kk)                   \
          acc[(mh) * 4 + m][(nh) * 2 + n] =                                \
              __builtin_amdgcn_mfma_f32_16x16x32_bf16(                     \
                  af[m][kk], BF[n][kk], acc[(mh) * 4 + m][(nh) * 2 + n],   \
                  0, 0, 0);                                                \
    __builtin_amdgcn_s_setprio(0);                                         \
  } while (0)

#define FENCE() asm volatile("" ::: "memory")

  f32x4 acc[8][4];
  #pragma unroll
  for (int i = 0; i < 8; ++i)
    #pragma unroll
    for (int j = 0; j < 4; ++j) acc[i][j] = (f32x4){0.f, 0.f, 0.f, 0.f};

  bf16x8 af[4][2], bf0[2][2], bf1[2][2];
  const int nt = K / 64;

  STAGE(0, 0, 0); STAGE(0, 1, 0); STAGE(0, 2, 0); STAGE(0, 3, 0);

  #pragma unroll 2
  for (int t = 0; t < nt; ++t) {
    const int buf = t & 1, ob = buf ^ 1;
    const int kbn = (t + 1) * 64;
    const bool pre = (t + 1 < nt);

    if (pre) {
      STAGE(ob, 0, kbn);
      asm volatile("s_waitcnt vmcnt(2)" ::: "memory");
    } else {
      asm volatile("s_waitcnt vmcnt(0)" ::: "memory");
    }
    __builtin_amdgcn_s_barrier(); FENCE();
    LDA_HALF(0); LDB_HALF(0, bf0);
    DO_QUAD(0, 0, bf0);
    __builtin_amdgcn_s_barrier(); FENCE();

    LDB_HALF(1, bf1);
    if (pre) STAGE(ob, 1, kbn);
    __builtin_amdgcn_s_barrier(); FENCE();
    DO_QUAD(0, 1, bf1);
    __builtin_amdgcn_s_barrier(); FENCE();

    LDA_HALF(1);
    if (pre) STAGE(ob, 2, kbn);
    __builtin_amdgcn_s_barrier(); FENCE();
    DO_QUAD(1, 1, bf1);
    __builtin_amdgcn_s_barrier(); FENCE();

    if (pre) STAGE(ob, 3, kbn);
    __builtin_amdgcn_s_barrier(); FENCE();
    DO_QUAD(1, 0, bf0);
    __builtin_amdgcn_s_barrier(); FENCE();
  }

#undef STAGE
#undef LDA_HALF
#undef LDB_HALF
#undef DO_QUAD
#undef FENCE

  const size_t crow0 = rowbase + (size_t)mi * 128;
  #pragma unroll
  for (int mt = 0; mt < 8; ++mt) {
    #pragma unroll
    for (int r = 0; r < 4; ++r) {
      size_t row = crow0 + mt * 16 + quad * 4 + r;
      #pragma unroll
      for (int nt_ = 0; nt_ < 4; ++nt_) {
        int col = colbase + ni * 64 + nt_ * 16 + n16;
        float v = acc[mt][nt_][r];
        if (MODE == 0) {
          ((float*)C0)[row * (size_t)N0 + col] = v;
        } else {
          if (col < N0) ((u16*)C0)[row * (size_t)N0 + col] = f2bf(v);
          else          ((u16*)C1)[row * (size_t)N1 + (col - N0)] = f2bf(v);
        }
      }
    }
  }
}

// ---------------- flash attention (causal, GQA), no-max softmax ------------
// Round-10: R1 body EXACTLY (f2bf scalar casts, per-element ternary mask,
// s_waitcnt(0) P-wait, no skip, no setprio, single-buffer + __syncthreads)
// plus ONLY the Vt XOR swizzle (the one change with a clean counter win:
// bank conflicts 5.57M -> 1.06M at one-XOR cost).
// Attribution from R1/R3/R8/R9: the {inline-asm cvt_pk + dead-tile skip}
// bundle costs ~70 µs (151 -> 220 at identical sync/grid/LDS) — consistent
// with the T12 catalog warning (m240: hand-written cvt_pk asm is -37% vs
// scalar casts; compiler scheduling defeated, VGPR 112->132).
__global__ __launch_bounds__(256) void attn_kernel(const u16* __restrict__ Qm,
                                                   const u16* __restrict__ KVm,
                                                   const u16* __restrict__ VTg,
                                                   u16* __restrict__ Ym) {
  __shared__ u16 Ks[32 * 128];
  __shared__ u16 Vt[128 * 32];
  __shared__ u16 Pb[4 * 32 * 40];

  const int tid = threadIdx.x;
  const int lane = tid & 63, wave = tid >> 6;
  const int quad = lane >> 4, n16 = lane & 15;
  const int b = blockIdx.y >> 4, h = blockIdx.y & 15;
  const int kvh = h >> 2;
  const int kvbase = b * TT;
  const u16* VTg_ = VTg + (size_t)((b * 4 + kvh) * 128) * TT;

  // K staging: XOR-16 chunk swizzle (conflict-free verified)
  const int krow = tid >> 4, kslot = tid & 15;
  const int kg = (kslot ^ krow) * 8;
  u16* Ksd0 = &Ks[krow * 128 + kslot * 8];      // byte = tid*16 (linear dest)
  u16* Ksd1 = &Ks[(krow + 16) * 128 + kslot * 8];
  // V staging: swizzle ci^((row>>1)&3); linear LDS dest, source carries swizzle.
  const int vrow = tid >> 2, vs = tid & 3;
  const int vq8 = (vs ^ ((tid >> 3) & 3)) * 8;
  u16* Vtd0 = &Vt[vrow * 32 + vs * 8];
  u16* Vtd1 = &Vt[(vrow + 64) * 32 + vs * 8];

  constexpr float SCL = 0.08838834764831843f * 1.4426950408889634f;

  for (int pass = 0; pass < 2; ++pass) {
    const int qt = pass ? 15 - (int)blockIdx.x : (int)blockIdx.x;
    const int q0 = qt * 128;
    const size_t qrowbase = (size_t)(b * TT + q0);
    const int wq0 = wave * 32;

    bf16x8 aq[2][4];
    #pragma unroll
    for (int mt = 0; mt < 2; ++mt) {
      const u16* qp = Qm + (qrowbase + wq0 + mt * 16 + n16) * (HH * DD) + h * DD + quad * 8;
      #pragma unroll
      for (int dt = 0; dt < 4; ++dt)
        aq[mt][dt] = *(const bf16x8*)(qp + dt * 32);
    }

    float lrow[2][4];
    f32x4 oacc[2][8];
    #pragma unroll
    for (int mt = 0; mt < 2; ++mt) {
      #pragma unroll
      for (int r = 0; r < 4; ++r) lrow[mt][r] = 0.f;
      #pragma unroll
      for (int i = 0; i < 8; ++i) oacc[mt][i] = (f32x4){0.f, 0.f, 0.f, 0.f};
    }

    const int kend = q0 + 128;
    for (int kb = 0; kb < kend; kb += 32) {
      __syncthreads();
      gl_lds16(KVm + (size_t)(kvbase + kb + krow) * 1024 + kvh * DD + kg, Ksd0);
      gl_lds16(KVm + (size_t)(kvbase + kb + krow + 16) * 1024 + kvh * DD + kg, Ksd1);
      gl_lds16(VTg_ + (size_t)vrow * TT + kb + vq8, Vtd0);
      gl_lds16(VTg_ + (size_t)(vrow + 64) * TT + kb + vq8, Vtd1);
      __syncthreads();

      // S = Q K^T : 2 m-tiles x 2 key-halves, K-frags shared across m
      f32x4 sf[2][2];
      #pragma unroll
      for (int half = 0; half < 2; ++half) {
        bf16x8 bk[4];
        #pragma unroll
        for (int dt = 0; dt < 4; ++dt) {
          int slot = (dt * 4 + quad) ^ n16;   // un-swizzle
          bk[dt] = *(const bf16x8*)&Ks[(half * 16 + n16) * 128 + slot * 8];
        }
        #pragma unroll
        for (int mt = 0; mt < 2; ++mt) {
          f32x4 s = (f32x4){0.f, 0.f, 0.f, 0.f};
          #pragma unroll
          for (int dt = 0; dt < 4; ++dt)
            s = __builtin_amdgcn_mfma_f32_16x16x32_bf16(aq[mt][dt], bk[dt], s, 0, 0, 0);
          sf[mt][half] = s;
        }
      }

      // p = exp2(s*scale*log2e) with causal mask; accumulate per-lane l; stash P
      u16* pw = &Pb[wave * (32 * 40)];
      #pragma unroll
      for (int mt = 0; mt < 2; ++mt)
        #pragma unroll
        for (int half = 0; half < 2; ++half) {
          int key = kb + half * 16 + n16;
          #pragma unroll
          for (int r = 0; r < 4; ++r) {
            int qpos = q0 + wq0 + mt * 16 + quad * 4 + r;
            float pv = (key <= qpos) ? exp2f(sf[mt][half][r] * SCL) : 0.f;
            lrow[mt][r] += pv;
            pw[(mt * 16 + quad * 4 + r) * 40 + half * 16 + n16] = f2bf(pv);
          }
        }
      __builtin_amdgcn_s_waitcnt(0);  // drain ds_writes before same-wave cross-lane read
      bf16x8 ap[2];
      ap[0] = *(const bf16x8*)&pw[n16 * 40 + quad * 8];
      ap[1] = *(const bf16x8*)&pw[(16 + n16) * 40 + quad * 8];

      // O += P V : V-frags shared across m-tiles (swizzled read)
      #pragma unroll
      for (int dt = 0; dt < 8; ++dt) {
        bf16x8 bv = *(const bf16x8*)&Vt[(dt * 16 + n16) * 32 +
                                        ((quad ^ ((n16 >> 1) & 3)) * 8)];
        oacc[0][dt] = __builtin_amdgcn_mfma_f32_16x16x32_bf16(ap[0], bv, oacc[0][dt], 0, 0, 0);
        oacc[1][dt] = __builtin_amdgcn_mfma_f32_16x16x32_bf16(ap[1], bv, oacc[1][dt], 0, 0, 0);
      }
    }

    // epilogue: reduce l across the 16 key-lanes, normalize, store
    float rinv[2][4];
    #pragma unroll
    for (int mt = 0; mt < 2; ++mt)
      #pragma unroll
      for (int r = 0; r < 4; ++r) {
        float v = lrow[mt][r];
        v += __shfl_xor(v, 1, 64);
        v += __shfl_xor(v, 2, 64);
        v += __shfl_xor(v, 4, 64);
        v += __shfl_xor(v, 8, 64);
        rinv[mt][r] = 1.0f / v;
      }
    #pragma unroll
    for (int mt = 0; mt < 2; ++mt)
      #pragma unroll
      for (int dt = 0; dt < 8; ++dt)
        #pragma unroll
        for (int r = 0; r < 4; ++r) {
          size_t row = qrowbase + wq0 + mt * 16 + quad * 4 + r;
          Ym[row * (HH * DD) + h * DD + dt * 16 + n16] = f2bf(oacc[mt][dt][r] * rinv[mt][r]);
        }
  }
}

// ---------------- launch ----------------
extern "C" void kernel_launch(void* const* d_in, const int* in_sizes, int n_in,
                              void* d_out, int out_size, void* d_ws, size_t ws_size,
                              hipStream_t stream) {
  const float* x  = (const float*)d_in[0];
  const float* Wq = (const float*)d_in[1];
  const float* Wk = (const float*)d_in[2];
  const float* Wv = (const float*)d_in[3];
  const float* Wo = (const float*)d_in[4];
  float* out = (float*)d_out;

  u16* ws   = (u16*)d_ws;
  u16* xb   = ws;                                  // 8192*2048 u16 (32 MiB)
  u16* Wbuf = xb + (size_t)8192 * 2048;            // 2048*2048 u16 (8 MiB)
  u16* Yb   = xb;                                  // alias: xb dead after QKV GEMM

  u16* ob   = (u16*)d_out;
  u16* Qb   = ob;                                                  // 32 MiB
  u16* KVb  = ob + (size_t)8192 * 2048;                            // 16 MiB
  u16* VTg  = ob + (size_t)8192 * 2048 + (size_t)8192 * 1024;      // 8 MiB
  u16* WkvT = VTg + (size_t)16 * 128 * 2048;                       // 4 MiB (1024x2048)

  cvt_f32_bf16<<<16384, 256, 0, stream>>>(x, xb, (4 * 2048 * 2048) / 4);

  transpose_w<<<dim3(64, 64), 256, 0, stream>>>(Wq, Wbuf, 2048, 2048);
  transpose_w<<<dim3(16, 64), 256, 0, stream>>>(Wk, WkvT, 2048, 512);
  transpose_w<<<dim3(16, 64), 256, 0, stream>>>(Wv, WkvT + (size_t)512 * 2048, 2048, 512);

  // fused [Q | KV] = x [Wq | Wk | Wv]   (N = 3072, grid 384)
  gemm256<1><<<384, 512, 0, stream>>>(xb, Wbuf, WkvT, (void*)Qb, (void*)KVb,
                                      8192, 2048, 1024, 2048, 12);

  transpose_v<<<dim3(64, 4, 16), 256, 0, stream>>>(KVb, VTg);

  attn_kernel<<<dim3(8, 64), 256, 0, stream>>>(Qb, KVb, VTg, Yb);

  transpose_w<<<dim3(64, 64), 256, 0, stream>>>(Wo, Wbuf, 2048, 2048);
  gemm256<0><<<256, 512, 0, stream>>>(Yb, Wbuf, nullptr, (void*)out, nullptr,
                                      8192, 2048, 0, 2048, 8);
}